// Round 3
// baseline (10553.336 us; speedup 1.0000x reference)
//
#include <hip/hip_runtime.h>
#include <hip/hip_bf16.h>

static constexpr int H   = 768;
static constexpr int R   = 16;
static constexpr int NL  = 3;
static constexpr int NS  = 64;
static constexpr int NT  = 256;   // N = NS + NQ
static constexpr int NHEADS = 8;
static constexpr int HD  = 96;

// ---------------------------------------------------------------------------
// build f = concat(support, query) in fp32
// ---------------------------------------------------------------------------
__global__ void build_f_kernel(const float* __restrict__ sup,
                               const float* __restrict__ qry,
                               float* __restrict__ f)
{
    int idx = blockIdx.x * blockDim.x + threadIdx.x;
    if (idx >= NT * H) return;
    f[idx] = idx < NS * H ? sup[idx] : qry[idx - NS * H];
}

// ---------------------------------------------------------------------------
// generic tiled GEMM: C[M,N] = op(A[M,K] @ (W[K,N] + sgn2*W2) + bias)
// all fp32. Batched via blockIdx.z with strides.
// 64x64 tile, BK=16, 256 threads, 4x4 micro-tile per thread.
// ---------------------------------------------------------------------------
__global__ __launch_bounds__(256)
void gemm64(const float* __restrict__ A, const float* __restrict__ W,
            const float* __restrict__ W2, float sgn2,
            const float* __restrict__ bias, float* __restrict__ C,
            int M, int Nn, int K, int lda, int ldw, int ldc,
            long long sA, long long sW, long long sC, long long sB, int relu)
{
    const int z = blockIdx.z;
    A += (long long)z * sA;
    C += (long long)z * sC;
    W += (long long)z * sW;
    if (bias) bias += (long long)z * sB;

    const int bm0 = blockIdx.x * 64, bn0 = blockIdx.y * 64;
    const int tid = threadIdx.x;
    const int tx = tid & 15, ty = tid >> 4;

    __shared__ float As[16][68];   // [k][m], padded row stride 68 (16B aligned)
    __shared__ float Bs[16][68];   // [k][n]

    float acc[4][4] = {};

    for (int kt = 0; kt < K; kt += 16) {
        #pragma unroll
        for (int u = 0; u < 4; ++u) {          // stage A tile: 64x16
            int e = tid + u * 256;
            int m = e >> 4, k = e & 15;
            int gm = bm0 + m, gk = kt + k;
            As[k][m] = (gm < M && gk < K) ? A[(long long)gm * lda + gk] : 0.f;
        }
        #pragma unroll
        for (int u = 0; u < 4; ++u) {          // stage B tile: 16x64
            int e = tid + u * 256;
            int k = e >> 6, n = e & 63;
            int gk = kt + k, gn = bn0 + n;
            float v = 0.f;
            if (gk < K && gn < Nn) {
                v = W[(long long)gk * ldw + gn];
                if (W2) v += sgn2 * W2[(long long)gk * ldw + gn];
            }
            Bs[k][n] = v;
        }
        __syncthreads();
        #pragma unroll
        for (int k = 0; k < 16; ++k) {
            const float4 a4 = *(const float4*)(&As[k][ty * 4]);
            const float4 b4 = *(const float4*)(&Bs[k][tx * 4]);
            float av[4] = {a4.x, a4.y, a4.z, a4.w};
            float bv[4] = {b4.x, b4.y, b4.z, b4.w};
            #pragma unroll
            for (int i = 0; i < 4; ++i)
                #pragma unroll
                for (int j = 0; j < 4; ++j)
                    acc[i][j] = fmaf(av[i], bv[j], acc[i][j]);
        }
        __syncthreads();
    }

    #pragma unroll
    for (int i = 0; i < 4; ++i) {
        int gm = bm0 + ty * 4 + i;
        if (gm >= M) continue;
        #pragma unroll
        for (int j = 0; j < 4; ++j) {
            int gn = bn0 + tx * 4 + j;
            if (gn >= Nn) continue;
            float c = acc[i][j];
            if (bias) c += bias[gn];
            if (relu) c = fmaxf(c, 0.f);
            C[(long long)gm * ldc + gn] = c;
        }
    }
}

// ---------------------------------------------------------------------------
// relations: per pair (i,j): h = relu(fa[i]+fb[j]+b1) (768), logits = h@w2+b2,
// softmax over R=16, mask diag; write fp32 out + wcoef-weighted comb (r-major)
// block = 256 threads = 8 i x 32 j pairs; k-chunks of 64 staged in LDS.
// ---------------------------------------------------------------------------
__global__ __launch_bounds__(256)
void relations_kernel(const float* __restrict__ fa, const float* __restrict__ fb,
                      const float* __restrict__ b1, const float* __restrict__ w2,
                      const float* __restrict__ b2,
                      float* __restrict__ out_rel, float* __restrict__ comb,
                      float wcoef, int accumulate)
{
    const int tid = threadIdx.x;
    const int i0 = blockIdx.x * 8, j0 = blockIdx.y * 32;
    const int il = tid >> 5, jl = tid & 31;

    __shared__ float fa_s[8][64];    // fa + b1
    __shared__ float fbT[64][33];    // [k][j], padded
    __shared__ float w2s[64][16];    // [k][r]

    float acc[16] = {};

    for (int kc = 0; kc < H; kc += 64) {
        #pragma unroll
        for (int u = 0; u < 2; ++u) {           // 8*64 = 512
            int e = tid + u * 256;
            int ii = e >> 6, k = e & 63;
            fa_s[ii][k] = fa[(i0 + ii) * H + kc + k] + b1[kc + k];
        }
        #pragma unroll
        for (int u = 0; u < 8; ++u) {           // 32*64 = 2048
            int e = tid + u * 256;
            int jj = e >> 6, k = e & 63;
            fbT[k][jj] = fb[(j0 + jj) * H + kc + k];
        }
        #pragma unroll
        for (int u = 0; u < 4; ++u) {           // 64*16 = 1024
            int e = tid + u * 256;
            int k = e >> 4, r = e & 15;
            w2s[k][r] = w2[(kc + k) * R + r];
        }
        __syncthreads();
        #pragma unroll 8
        for (int k = 0; k < 64; ++k) {
            float hv = fmaxf(fa_s[il][k] + fbT[k][jl], 0.f);
            const float4* wr = (const float4*)(&w2s[k][0]);
            float4 w0 = wr[0], w1 = wr[1], w2_ = wr[2], w3 = wr[3];
            acc[0]  = fmaf(hv, w0.x, acc[0]);   acc[1]  = fmaf(hv, w0.y, acc[1]);
            acc[2]  = fmaf(hv, w0.z, acc[2]);   acc[3]  = fmaf(hv, w0.w, acc[3]);
            acc[4]  = fmaf(hv, w1.x, acc[4]);   acc[5]  = fmaf(hv, w1.y, acc[5]);
            acc[6]  = fmaf(hv, w1.z, acc[6]);   acc[7]  = fmaf(hv, w1.w, acc[7]);
            acc[8]  = fmaf(hv, w2_.x, acc[8]);  acc[9]  = fmaf(hv, w2_.y, acc[9]);
            acc[10] = fmaf(hv, w2_.z, acc[10]); acc[11] = fmaf(hv, w2_.w, acc[11]);
            acc[12] = fmaf(hv, w3.x, acc[12]);  acc[13] = fmaf(hv, w3.y, acc[13]);
            acc[14] = fmaf(hv, w3.z, acc[14]);  acc[15] = fmaf(hv, w3.w, acc[15]);
        }
        __syncthreads();
    }

    const int gi = i0 + il, gj = j0 + jl;
    float mx = -1e30f;
    #pragma unroll
    for (int r = 0; r < 16; ++r) { acc[r] += b2[r]; mx = fmaxf(mx, acc[r]); }
    float p[16], sum = 0.f;
    #pragma unroll
    for (int r = 0; r < 16; ++r) { p[r] = expf(acc[r] - mx); sum += p[r]; }
    const float inv = (gi == gj) ? 0.f : (1.f / sum);   // softmax + diagonal mask

    float* orow = out_rel + ((long long)gi * NT + gj) * R;
    #pragma unroll
    for (int r = 0; r < 16; ++r) {
        float val = p[r] * inv;
        orow[r] = val;
        float* cp = comb + ((long long)r << 16) + gi * NT + gj;  // comb[r][i][j]
        if (accumulate) *cp += wcoef * val;
        else            *cp  = wcoef * val;
    }
}

// ---------------------------------------------------------------------------
// layernorm over H=768: out = (in(+res) - mean) * rsqrt(var+1e-5) * g + b
// one block (256 thr) per row
// ---------------------------------------------------------------------------
__global__ __launch_bounds__(256)
void ln_kernel(const float* __restrict__ in, const float* __restrict__ res,
               const float* __restrict__ g, const float* __restrict__ b,
               float* __restrict__ out)
{
    const int row = blockIdx.x, tid = threadIdx.x;
    const long long base = (long long)row * H;
    float v[3], s = 0.f, s2 = 0.f;
    #pragma unroll
    for (int e = 0; e < 3; ++e) {
        int c = tid + e * 256;
        float x = in[base + c];
        if (res) x += res[base + c];
        v[e] = x; s += x; s2 += x * x;
    }
    #pragma unroll
    for (int off = 32; off; off >>= 1) {
        s  += __shfl_down(s, off);
        s2 += __shfl_down(s2, off);
    }
    __shared__ float rs[4], rq[4], mv[2];
    if ((tid & 63) == 0) { rs[tid >> 6] = s; rq[tid >> 6] = s2; }
    __syncthreads();
    if (tid == 0) {
        float a  = rs[0] + rs[1] + rs[2] + rs[3];
        float a2 = rq[0] + rq[1] + rq[2] + rq[3];
        float mean = a * (1.f / H);
        float var  = a2 * (1.f / H) - mean * mean;
        mv[0] = mean; mv[1] = rsqrtf(var + 1e-5f);
    }
    __syncthreads();
    const float mean = mv[0], rstd = mv[1];
    #pragma unroll
    for (int e = 0; e < 3; ++e) {
        int c = tid + e * 256;
        out[base + c] = (v[e] - mean) * rstd * g[c] + b[c];
    }
}

// ---------------------------------------------------------------------------
// transpose 256x768 -> 768x256 (for coalesced k-column reads in attention)
// ---------------------------------------------------------------------------
__global__ void transpose_kernel(const float* __restrict__ in, float* __restrict__ out,
                                 int rows, int cols)
{
    __shared__ float t[32][33];
    int x = blockIdx.x * 32 + threadIdx.x;   // col
    int y = blockIdx.y * 32 + threadIdx.y;   // row
    t[threadIdx.y][threadIdx.x] = in[y * cols + x];
    __syncthreads();
    int orow = blockIdx.x * 32 + threadIdx.y;   // col of in
    int ocol = blockIdx.y * 32 + threadIdx.x;   // row of in
    out[orow * rows + ocol] = t[threadIdx.x][threadIdx.y];
}

// ---------------------------------------------------------------------------
// attention: grid (head, i); S-row in LDS, block softmax, o accumulation
// ---------------------------------------------------------------------------
__global__ __launch_bounds__(256)
void attn_kernel(const float* __restrict__ q, const float* __restrict__ kT,
                 const float* __restrict__ v, float* __restrict__ o)
{
    const int h = blockIdx.x, i = blockIdx.y, tid = threadIdx.x;
    __shared__ float qs[HD];
    __shared__ float sc[NT];
    __shared__ float red[4];
    __shared__ float fmx, fsum;

    if (tid < HD) qs[tid] = q[i * H + h * HD + tid];
    __syncthreads();

    float s = 0.f;
    const float* kcol = kT + (h * HD) * NT + tid;
    #pragma unroll 4
    for (int d = 0; d < HD; ++d) s = fmaf(qs[d], kcol[d * NT], s);
    s *= 0.10206207261596577f;   // 1/sqrt(96)

    float m = s;
    #pragma unroll
    for (int off = 32; off; off >>= 1) m = fmaxf(m, __shfl_down(m, off));
    if ((tid & 63) == 0) red[tid >> 6] = m;
    __syncthreads();
    if (tid == 0) fmx = fmaxf(fmaxf(red[0], red[1]), fmaxf(red[2], red[3]));
    __syncthreads();

    float p = expf(s - fmx);
    sc[tid] = p;
    float ss = p;
    #pragma unroll
    for (int off = 32; off; off >>= 1) ss += __shfl_down(ss, off);
    if ((tid & 63) == 0) red[tid >> 6] = ss;
    __syncthreads();
    if (tid == 0) fsum = red[0] + red[1] + red[2] + red[3];
    __syncthreads();

    if (tid < HD) {
        float a = 0.f;
        const float* vcol = v + h * HD + tid;
        for (int j = 0; j < NT; ++j) a = fmaf(sc[j], vcol[j * H], a);
        o[i * H + h * HD + tid] = a / fsum;
    }
}

// ---------------------------------------------------------------------------
// classifier final: preds[i][c] = hid[i] . cls_w2[:,c] + b2[c]; 1 wave per row
// ---------------------------------------------------------------------------
__global__ __launch_bounds__(64)
void cls_final_kernel(const float* __restrict__ hid, const float* __restrict__ w2,
                      const float* __restrict__ b2, float* __restrict__ preds)
{
    const int i = blockIdx.x, lane = threadIdx.x;
    float a0 = 0.f, a1 = 0.f, a2 = 0.f;
    for (int k = lane; k < 384; k += 64) {
        float hv = hid[i * 384 + k];
        a0 = fmaf(hv, w2[k * 3 + 0], a0);
        a1 = fmaf(hv, w2[k * 3 + 1], a1);
        a2 = fmaf(hv, w2[k * 3 + 2], a2);
    }
    #pragma unroll
    for (int off = 32; off; off >>= 1) {
        a0 += __shfl_down(a0, off);
        a1 += __shfl_down(a1, off);
        a2 += __shfl_down(a2, off);
    }
    if (lane == 0) {
        preds[i * 3 + 0] = a0 + b2[0];
        preds[i * 3 + 1] = a1 + b2[1];
        preds[i * 3 + 2] = a2 + b2[2];
    }
}

// ---------------------------------------------------------------------------
// host
// ---------------------------------------------------------------------------
static void gemm(hipStream_t st, const float* A, const float* W, const float* W2, float sgn,
                 const float* bias, float* C, int M, int Nn, int K,
                 int lda, int ldw, int ldc,
                 long long sA, long long sW, long long sC, long long sB,
                 int relu, int batches)
{
    dim3 grid((M + 63) / 64, (Nn + 63) / 64, batches);
    gemm64<<<grid, 256, 0, st>>>(A, W, W2, sgn, bias, C,
                                 M, Nn, K, lda, ldw, ldc, sA, sW, sC, sB, relu);
}

extern "C" void kernel_launch(void* const* d_in, const int* in_sizes, int n_in,
                              void* d_out, int out_size, void* d_ws, size_t ws_size,
                              hipStream_t stream)
{
    const float* sup    = (const float*)d_in[0];
    const float* qry    = (const float*)d_in[1];
    // d_in[2] support_labels: unused by reference
    const float* sim_w1 = (const float*)d_in[3];
    const float* sim_b1 = (const float*)d_in[4];
    const float* sim_w2 = (const float*)d_in[5];
    const float* sim_b2 = (const float*)d_in[6];
    const float* div_w1 = (const float*)d_in[7];
    const float* div_b1 = (const float*)d_in[8];
    const float* div_w2 = (const float*)d_in[9];
    const float* div_b2 = (const float*)d_in[10];
    const float* dis_w1 = (const float*)d_in[11];
    const float* dis_b1 = (const float*)d_in[12];
    const float* dis_w2 = (const float*)d_in[13];
    const float* dis_b2 = (const float*)d_in[14];
    const float* dis_g  = (const float*)d_in[15];
    const float* dis_bb = (const float*)d_in[16];
    const float* rel_W  = (const float*)d_in[17];
    const float* rel_b  = (const float*)d_in[18];
    const float* agg_w1 = (const float*)d_in[19];
    const float* agg_b1 = (const float*)d_in[20];
    const float* agg_w2 = (const float*)d_in[21];
    const float* agg_b2 = (const float*)d_in[22];
    const float* wq = (const float*)d_in[23];
    const float* bq = (const float*)d_in[24];
    const float* wk = (const float*)d_in[25];
    const float* bk = (const float*)d_in[26];
    const float* wv = (const float*)d_in[27];
    const float* bv = (const float*)d_in[28];
    const float* wo = (const float*)d_in[29];
    const float* bo = (const float*)d_in[30];
    const float* ln_g = (const float*)d_in[31];
    const float* ln_b = (const float*)d_in[32];
    const float* cls_w1 = (const float*)d_in[33];
    const float* cls_b1 = (const float*)d_in[34];
    const float* cls_w2 = (const float*)d_in[35];
    const float* cls_b2 = (const float*)d_in[36];

    const int NH = NT * H;          // 196608
    const int HH = H * H;           // 589824

    // workspace layout (fp32)
    float* ws = (float*)d_ws;
    float* f       = ws;
    float* fa_s    = f      + NH;
    float* fb_s    = fa_s   + NH;
    float* fa_d    = fb_s   + NH;
    float* fb_d    = fa_d   + NH;
    float* comb    = fb_d   + NH;          // 16*256*256 = 1048576, layout [r][i][j]
    float* xA      = comb   + 1048576;
    float* xB      = xA     + NH;
    float* hid384  = xB     + NH;          // 256*384
    float* t_buf   = hid384 + 98304;       // 16*256*768
    float* agg     = t_buf  + 3145728;     // 256*12288
    float* hidA    = agg    + 3145728;
    float* a_buf   = hidA   + NH;
    float* q_buf   = a_buf  + NH;
    float* k_buf   = q_buf  + NH;
    float* kT_buf  = k_buf  + NH;
    float* v_buf   = kT_buf + NH;
    float* o_buf   = v_buf  + NH;
    float* tmp_o   = o_buf  + NH;
    float* cls_hid = tmp_o  + NH;          // 192*384
    size_t need = (size_t)((cls_hid + 73728) - ws) * sizeof(float);
    if (ws_size < need) return;            // ws too small: leave poison -> loud failure

    // output layout (fp32): preds(576), x(196608), sim(1048576), div(1048576)
    float* out       = (float*)d_out;
    float* out_preds = out;
    float* out_x     = out + 576;
    float* out_sim   = out_x + NH;
    float* out_div   = out_sim + 1048576;

    // 1. f = concat
    build_f_kernel<<<(NH + 255) / 256, 256, 0, stream>>>(sup, qry, f);

    // 2. fa/fb for sim and div   (div: wa' = da+db, wb' = db-da)
    gemm(stream, f, sim_w1,        nullptr, 0.f,  nullptr, fa_s, NT, H, H, H, H, H, 0,0,0,0, 0, 1);
    gemm(stream, f, sim_w1 + HH,   nullptr, 0.f,  nullptr, fb_s, NT, H, H, H, H, H, 0,0,0,0, 0, 1);
    gemm(stream, f, div_w1,        div_w1 + HH,  1.f, nullptr, fa_d, NT, H, H, H, H, H, 0,0,0,0, 0, 1);
    gemm(stream, f, div_w1 + HH,   div_w1,      -1.f, nullptr, fb_d, NT, H, H, H, H, H, 0,0,0,0, 0, 1);

    // 3. relations (sim writes comb, div accumulates)
    relations_kernel<<<dim3(32, 8), 256, 0, stream>>>(fa_s, fb_s, sim_b1, sim_w2, sim_b2,
                                                      out_sim, comb, 0.6f, 0);
    relations_kernel<<<dim3(32, 8), 256, 0, stream>>>(fa_d, fb_d, div_b1, div_w2, div_b2,
                                                      out_div, comb, 0.4f, 1);

    // 4. distill MLP + LN -> x
    gemm(stream, f, dis_w1, nullptr, 0.f, dis_b1, hid384, NT, 384, H, H, 384, 384, 0,0,0,0, 1, 1);
    gemm(stream, hid384, dis_w2, nullptr, 0.f, dis_b2, tmp_o, NT, H, 384, 384, H, H, 0,0,0,0, 0, 1);
    ln_kernel<<<NT, 256, 0, stream>>>(tmp_o, nullptr, dis_g, dis_bb, xA);

    float* x_cur = xA;
    float* x_nxt = xB;
    for (int l = 0; l < NL; ++l) {
        const float* relW_l = rel_W + (long long)l * R * HH;
        const float* relb_l = rel_b + l * R * H;
        // t[r] = x @ rel_W[l,r] + rel_b[l,r]   (16 batches)
        gemm(stream, x_cur, relW_l, nullptr, 0.f, relb_l, t_buf,
             NT, H, H, H, H, H, 0, (long long)HH, (long long)NH, H, 0, R);
        // agg[i, r*H+h] = sum_j comb[r,i,j] * t[r,j,h]   (16 batches)
        gemm(stream, comb, t_buf, nullptr, 0.f, nullptr, agg,
             NT, H, NT, NT, H, R * H, (long long)NT * NT, (long long)NH, H, 0, 0, R);
        // agg MLP
        gemm(stream, agg, agg_w1 + (long long)l * R * H * H, nullptr, 0.f,
             agg_b1 + l * H, hidA, NT, H, R * H, R * H, H, H, 0,0,0,0, 1, 1);
        gemm(stream, hidA, agg_w2 + (long long)l * HH, nullptr, 0.f,
             agg_b2 + l * H, a_buf, NT, H, H, H, H, H, 0,0,0,0, 0, 1);
        // q from a, k/v from x
        gemm(stream, a_buf, wq + (long long)l * HH, nullptr, 0.f, bq + l * H, q_buf,
             NT, H, H, H, H, H, 0,0,0,0, 0, 1);
        gemm(stream, x_cur, wk + (long long)l * HH, nullptr, 0.f, bk + l * H, k_buf,
             NT, H, H, H, H, H, 0,0,0,0, 0, 1);
        gemm(stream, x_cur, wv + (long long)l * HH, nullptr, 0.f, bv + l * H, v_buf,
             NT, H, H, H, H, H, 0,0,0,0, 0, 1);
        transpose_kernel<<<dim3(H / 32, NT / 32), dim3(32, 32), 0, stream>>>(k_buf, kT_buf, NT, H);
        attn_kernel<<<dim3(NHEADS, NT), 256, 0, stream>>>(q_buf, kT_buf, v_buf, o_buf);
        gemm(stream, o_buf, wo + (long long)l * HH, nullptr, 0.f, bo + l * H, tmp_o,
             NT, H, H, H, H, H, 0,0,0,0, 0, 1);
        float* dst = (l == NL - 1) ? out_x : x_nxt;   // last layer writes x output directly
        ln_kernel<<<NT, 256, 0, stream>>>(tmp_o, x_cur, ln_g + l * H, ln_b + l * H, dst);
        x_nxt = x_cur; x_cur = dst;
    }

    // classifier on query rows (reads from out_x region, fp32)
    gemm(stream, x_cur + (long long)NS * H, cls_w1, nullptr, 0.f, cls_b1, cls_hid,
         192, 384, H, H, 384, 384, 0,0,0,0, 1, 1);
    cls_final_kernel<<<192, 64, 0, stream>>>(cls_hid, cls_w2, cls_b2, out_preds);
}

// Round 4
// 1443.367 us; speedup vs baseline: 7.3116x; 7.3116x over previous
//
#include <hip/hip_runtime.h>
#include <hip/hip_bf16.h>

static constexpr int H   = 768;
static constexpr int R   = 16;
static constexpr int NL  = 3;
static constexpr int NS  = 64;
static constexpr int NT  = 256;   // N = NS + NQ
static constexpr int NHEADS = 8;
static constexpr int HD  = 96;

// ---------------------------------------------------------------------------
// build f = concat(support, query) in fp32
// ---------------------------------------------------------------------------
__global__ void build_f_kernel(const float* __restrict__ sup,
                               const float* __restrict__ qry,
                               float* __restrict__ f)
{
    int idx = blockIdx.x * blockDim.x + threadIdx.x;
    if (idx >= NT * H) return;
    f[idx] = idx < NS * H ? sup[idx] : qry[idx - NS * H];
}

// ---------------------------------------------------------------------------
// generic tiled GEMM: C[M,N] = op(A[M,K] @ (W[K,N] + sgn2*W2) + bias)
// fp32, 64x64 tile, BK=16, 256 threads, 4x4 micro-tile per thread.
// Requires M%64==0 (or grid covers M), Nn%64==0, K%16==0, kc%16==0.
// Two z-modes: ksplit==1 -> z is batch index (strided A/W/C/bias);
//              ksplit>1  -> z is K-split index, partials written to part.
// Software-pipelined: next K-tile prefetched into registers during compute.
// ---------------------------------------------------------------------------
__global__ __launch_bounds__(256)
void gemm64(const float* __restrict__ A, const float* __restrict__ W,
            const float* __restrict__ W2, float sgn2,
            const float* __restrict__ bias, float* __restrict__ C,
            float* __restrict__ part,
            int M, int Nn, int K, int lda, int ldw, int ldc,
            long long sA, long long sW, long long sC, long long sB,
            int relu, int ksplit, int kc)
{
    const int tid = threadIdx.x;
    const int bm0 = blockIdx.x * 64, bn0 = blockIdx.y * 64;
    const int z = blockIdx.z;

    int k0 = 0, kend = K;
    if (ksplit > 1) {
        k0 = z * kc;
        kend = min(K, k0 + kc);
        if (k0 >= kend) return;   // defensive (never hit with our configs)
    } else {
        A += (long long)z * sA;
        W += (long long)z * sW;
        C += (long long)z * sC;
        if (bias) bias += (long long)z * sB;
    }

    const int tx = tid & 15, ty = tid >> 4;       // output micro-tile coords
    const int am = tid >> 2, ak = (tid & 3) * 4;  // A staging: row am, 4 k's
    const int bk = tid >> 4, bn = (tid & 15) * 4; // B staging: k-row bk, 4 n's

    __shared__ float As[16][68];   // [k][m]
    __shared__ float Bs[16][68];   // [k][n]

    const float* Aptr  = A + (long long)(bm0 + am) * lda + ak;
    const float* Wptr  = W + (long long)bk * ldw + bn0 + bn;
    const float* W2ptr = W2 ? W2 + (long long)bk * ldw + bn0 + bn : nullptr;

    float4 apf = *(const float4*)(Aptr + k0);
    float4 bpf = *(const float4*)(Wptr + (long long)k0 * ldw);
    if (W2ptr) {
        float4 w = *(const float4*)(W2ptr + (long long)k0 * ldw);
        bpf.x += sgn2 * w.x; bpf.y += sgn2 * w.y;
        bpf.z += sgn2 * w.z; bpf.w += sgn2 * w.w;
    }

    float acc[4][4] = {};

    for (int kt = k0; kt < kend; kt += 16) {
        As[ak + 0][am] = apf.x; As[ak + 1][am] = apf.y;
        As[ak + 2][am] = apf.z; As[ak + 3][am] = apf.w;
        *(float4*)&Bs[bk][bn] = bpf;
        __syncthreads();

        const int kn = kt + 16;
        if (kn < kend) {           // prefetch next tile (loads in flight over compute)
            apf = *(const float4*)(Aptr + kn);
            bpf = *(const float4*)(Wptr + (long long)kn * ldw);
            if (W2ptr) {
                float4 w = *(const float4*)(W2ptr + (long long)kn * ldw);
                bpf.x += sgn2 * w.x; bpf.y += sgn2 * w.y;
                bpf.z += sgn2 * w.z; bpf.w += sgn2 * w.w;
            }
        }

        #pragma unroll
        for (int k = 0; k < 16; ++k) {
            const float4 a4 = *(const float4*)(&As[k][ty * 4]);
            const float4 b4 = *(const float4*)(&Bs[k][tx * 4]);
            float av[4] = {a4.x, a4.y, a4.z, a4.w};
            float bv[4] = {b4.x, b4.y, b4.z, b4.w};
            #pragma unroll
            for (int i = 0; i < 4; ++i)
                #pragma unroll
                for (int j = 0; j < 4; ++j)
                    acc[i][j] = fmaf(av[i], bv[j], acc[i][j]);
        }
        __syncthreads();
    }

    if (ksplit > 1) {
        float* P = part + (long long)z * M * Nn;
        #pragma unroll
        for (int i = 0; i < 4; ++i) {
            int gm = bm0 + ty * 4 + i;
            float4 c = {acc[i][0], acc[i][1], acc[i][2], acc[i][3]};
            *(float4*)&P[(long long)gm * Nn + bn0 + tx * 4] = c;
        }
    } else {
        #pragma unroll
        for (int i = 0; i < 4; ++i) {
            int gm = bm0 + ty * 4 + i;
            int gn = bn0 + tx * 4;
            float4 c = {acc[i][0], acc[i][1], acc[i][2], acc[i][3]};
            if (bias) {
                c.x += bias[gn]; c.y += bias[gn + 1];
                c.z += bias[gn + 2]; c.w += bias[gn + 3];
            }
            if (relu) {
                c.x = fmaxf(c.x, 0.f); c.y = fmaxf(c.y, 0.f);
                c.z = fmaxf(c.z, 0.f); c.w = fmaxf(c.w, 0.f);
            }
            *(float4*)&C[(long long)gm * ldc + gn] = c;
        }
    }
}

// ---------------------------------------------------------------------------
// reduce K-split partials: C[m,n] = op(sum_k part[k][m][n] + bias[n])
// ---------------------------------------------------------------------------
__global__ __launch_bounds__(256)
void ksum_kernel(const float* __restrict__ part, const float* __restrict__ bias,
                 float* __restrict__ C, int M, int Nn, int ldc, int ksplit, int relu)
{
    int idx4 = blockIdx.x * 256 + threadIdx.x;
    int total = (M * Nn) >> 2;
    if (idx4 >= total) return;
    int idx = idx4 << 2;
    int m = idx / Nn, n = idx - m * Nn;
    float4 s = {0.f, 0.f, 0.f, 0.f};
    for (int k = 0; k < ksplit; ++k) {
        float4 p = *(const float4*)&part[(long long)k * M * Nn + idx];
        s.x += p.x; s.y += p.y; s.z += p.z; s.w += p.w;
    }
    if (bias) {
        s.x += bias[n]; s.y += bias[n + 1]; s.z += bias[n + 2]; s.w += bias[n + 3];
    }
    if (relu) {
        s.x = fmaxf(s.x, 0.f); s.y = fmaxf(s.y, 0.f);
        s.z = fmaxf(s.z, 0.f); s.w = fmaxf(s.w, 0.f);
    }
    *(float4*)&C[(long long)m * ldc + n] = s;
}

// ---------------------------------------------------------------------------
// relations: per pair (i,j): h = relu(fa[i]+fb[j]+b1) (768), logits = h@w2+b2,
// softmax over R=16, mask diag; write fp32 out + wcoef-weighted comb (r-major)
// block = 256 threads = 8 i x 32 j pairs; k-chunks of 64 staged in LDS.
// ---------------------------------------------------------------------------
__global__ __launch_bounds__(256)
void relations_kernel(const float* __restrict__ fa, const float* __restrict__ fb,
                      const float* __restrict__ b1, const float* __restrict__ w2,
                      const float* __restrict__ b2,
                      float* __restrict__ out_rel, float* __restrict__ comb,
                      float wcoef, int accumulate)
{
    const int tid = threadIdx.x;
    const int i0 = blockIdx.x * 8, j0 = blockIdx.y * 32;
    const int il = tid >> 5, jl = tid & 31;

    __shared__ float fa_s[8][64];    // fa + b1
    __shared__ float fbT[64][33];    // [k][j], padded
    __shared__ float w2s[64][16];    // [k][r]

    float acc[16] = {};

    for (int kc = 0; kc < H; kc += 64) {
        #pragma unroll
        for (int u = 0; u < 2; ++u) {           // 8*64 = 512
            int e = tid + u * 256;
            int ii = e >> 6, k = e & 63;
            fa_s[ii][k] = fa[(i0 + ii) * H + kc + k] + b1[kc + k];
        }
        #pragma unroll
        for (int u = 0; u < 8; ++u) {           // 32*64 = 2048
            int e = tid + u * 256;
            int jj = e >> 6, k = e & 63;
            fbT[k][jj] = fb[(j0 + jj) * H + kc + k];
        }
        #pragma unroll
        for (int u = 0; u < 4; ++u) {           // 64*16 = 1024
            int e = tid + u * 256;
            int k = e >> 4, r = e & 15;
            w2s[k][r] = w2[(kc + k) * R + r];
        }
        __syncthreads();
        #pragma unroll 8
        for (int k = 0; k < 64; ++k) {
            float hv = fmaxf(fa_s[il][k] + fbT[k][jl], 0.f);
            const float4* wr = (const float4*)(&w2s[k][0]);
            float4 w0 = wr[0], w1 = wr[1], w2_ = wr[2], w3 = wr[3];
            acc[0]  = fmaf(hv, w0.x, acc[0]);   acc[1]  = fmaf(hv, w0.y, acc[1]);
            acc[2]  = fmaf(hv, w0.z, acc[2]);   acc[3]  = fmaf(hv, w0.w, acc[3]);
            acc[4]  = fmaf(hv, w1.x, acc[4]);   acc[5]  = fmaf(hv, w1.y, acc[5]);
            acc[6]  = fmaf(hv, w1.z, acc[6]);   acc[7]  = fmaf(hv, w1.w, acc[7]);
            acc[8]  = fmaf(hv, w2_.x, acc[8]);  acc[9]  = fmaf(hv, w2_.y, acc[9]);
            acc[10] = fmaf(hv, w2_.z, acc[10]); acc[11] = fmaf(hv, w2_.w, acc[11]);
            acc[12] = fmaf(hv, w3.x, acc[12]);  acc[13] = fmaf(hv, w3.y, acc[13]);
            acc[14] = fmaf(hv, w3.z, acc[14]);  acc[15] = fmaf(hv, w3.w, acc[15]);
        }
        __syncthreads();
    }

    const int gi = i0 + il, gj = j0 + jl;
    float mx = -1e30f;
    #pragma unroll
    for (int r = 0; r < 16; ++r) { acc[r] += b2[r]; mx = fmaxf(mx, acc[r]); }
    float p[16], sum = 0.f;
    #pragma unroll
    for (int r = 0; r < 16; ++r) { p[r] = expf(acc[r] - mx); sum += p[r]; }
    const float inv = (gi == gj) ? 0.f : (1.f / sum);   // softmax + diagonal mask

    float* orow = out_rel + ((long long)gi * NT + gj) * R;
    #pragma unroll
    for (int r = 0; r < 16; ++r) {
        float val = p[r] * inv;
        orow[r] = val;
        float* cp = comb + ((long long)r << 16) + gi * NT + gj;  // comb[r][i][j]
        if (accumulate) *cp += wcoef * val;
        else            *cp  = wcoef * val;
    }
}

// ---------------------------------------------------------------------------
// layernorm over H=768
// ---------------------------------------------------------------------------
__global__ __launch_bounds__(256)
void ln_kernel(const float* __restrict__ in, const float* __restrict__ res,
               const float* __restrict__ g, const float* __restrict__ b,
               float* __restrict__ out)
{
    const int row = blockIdx.x, tid = threadIdx.x;
    const long long base = (long long)row * H;
    float v[3], s = 0.f, s2 = 0.f;
    #pragma unroll
    for (int e = 0; e < 3; ++e) {
        int c = tid + e * 256;
        float x = in[base + c];
        if (res) x += res[base + c];
        v[e] = x; s += x; s2 += x * x;
    }
    #pragma unroll
    for (int off = 32; off; off >>= 1) {
        s  += __shfl_down(s, off);
        s2 += __shfl_down(s2, off);
    }
    __shared__ float rs[4], rq[4], mv[2];
    if ((tid & 63) == 0) { rs[tid >> 6] = s; rq[tid >> 6] = s2; }
    __syncthreads();
    if (tid == 0) {
        float a  = rs[0] + rs[1] + rs[2] + rs[3];
        float a2 = rq[0] + rq[1] + rq[2] + rq[3];
        float mean = a * (1.f / H);
        float var  = a2 * (1.f / H) - mean * mean;
        mv[0] = mean; mv[1] = rsqrtf(var + 1e-5f);
    }
    __syncthreads();
    const float mean = mv[0], rstd = mv[1];
    #pragma unroll
    for (int e = 0; e < 3; ++e) {
        int c = tid + e * 256;
        out[base + c] = (v[e] - mean) * rstd * g[c] + b[c];
    }
}

// ---------------------------------------------------------------------------
// transpose 256x768 -> 768x256
// ---------------------------------------------------------------------------
__global__ void transpose_kernel(const float* __restrict__ in, float* __restrict__ out,
                                 int rows, int cols)
{
    __shared__ float t[32][33];
    int x = blockIdx.x * 32 + threadIdx.x;
    int y = blockIdx.y * 32 + threadIdx.y;
    t[threadIdx.y][threadIdx.x] = in[y * cols + x];
    __syncthreads();
    int orow = blockIdx.x * 32 + threadIdx.y;
    int ocol = blockIdx.y * 32 + threadIdx.x;
    out[orow * rows + ocol] = t[threadIdx.x][threadIdx.y];
}

// ---------------------------------------------------------------------------
// attention: grid (head, i)
// ---------------------------------------------------------------------------
__global__ __launch_bounds__(256)
void attn_kernel(const float* __restrict__ q, const float* __restrict__ kT,
                 const float* __restrict__ v, float* __restrict__ o)
{
    const int h = blockIdx.x, i = blockIdx.y, tid = threadIdx.x;
    __shared__ float qs[HD];
    __shared__ float sc[NT];
    __shared__ float red[4];
    __shared__ float fmx, fsum;

    if (tid < HD) qs[tid] = q[i * H + h * HD + tid];
    __syncthreads();

    float s = 0.f;
    const float* kcol = kT + (h * HD) * NT + tid;
    #pragma unroll 4
    for (int d = 0; d < HD; ++d) s = fmaf(qs[d], kcol[d * NT], s);
    s *= 0.10206207261596577f;   // 1/sqrt(96)

    float m = s;
    #pragma unroll
    for (int off = 32; off; off >>= 1) m = fmaxf(m, __shfl_down(m, off));
    if ((tid & 63) == 0) red[tid >> 6] = m;
    __syncthreads();
    if (tid == 0) fmx = fmaxf(fmaxf(red[0], red[1]), fmaxf(red[2], red[3]));
    __syncthreads();

    float p = expf(s - fmx);
    sc[tid] = p;
    float ss = p;
    #pragma unroll
    for (int off = 32; off; off >>= 1) ss += __shfl_down(ss, off);
    if ((tid & 63) == 0) red[tid >> 6] = ss;
    __syncthreads();
    if (tid == 0) fsum = red[0] + red[1] + red[2] + red[3];
    __syncthreads();

    if (tid < HD) {
        float a = 0.f;
        const float* vcol = v + h * HD + tid;
        for (int j = 0; j < NT; ++j) a = fmaf(sc[j], vcol[j * H], a);
        o[i * H + h * HD + tid] = a / fsum;
    }
}

// ---------------------------------------------------------------------------
// classifier final
// ---------------------------------------------------------------------------
__global__ __launch_bounds__(64)
void cls_final_kernel(const float* __restrict__ hid, const float* __restrict__ w2,
                      const float* __restrict__ b2, float* __restrict__ preds)
{
    const int i = blockIdx.x, lane = threadIdx.x;
    float a0 = 0.f, a1 = 0.f, a2 = 0.f;
    for (int k = lane; k < 384; k += 64) {
        float hv = hid[i * 384 + k];
        a0 = fmaf(hv, w2[k * 3 + 0], a0);
        a1 = fmaf(hv, w2[k * 3 + 1], a1);
        a2 = fmaf(hv, w2[k * 3 + 2], a2);
    }
    #pragma unroll
    for (int off = 32; off; off >>= 1) {
        a0 += __shfl_down(a0, off);
        a1 += __shfl_down(a1, off);
        a2 += __shfl_down(a2, off);
    }
    if (lane == 0) {
        preds[i * 3 + 0] = a0 + b2[0];
        preds[i * 3 + 1] = a1 + b2[1];
        preds[i * 3 + 2] = a2 + b2[2];
    }
}

// ---------------------------------------------------------------------------
// host
// ---------------------------------------------------------------------------
static void gemm(hipStream_t st, const float* A, const float* W, const float* W2, float sgn,
                 const float* bias, float* C, float* part, int M, int Nn, int K,
                 int lda, int ldw, int ldc,
                 long long sA, long long sW, long long sC, long long sB,
                 int relu, int batches, int ksplit)
{
    if (ksplit <= 1) {
        dim3 grid(M / 64, Nn / 64, batches);
        gemm64<<<grid, 256, 0, st>>>(A, W, W2, sgn, bias, C, nullptr,
                                     M, Nn, K, lda, ldw, ldc, sA, sW, sC, sB,
                                     relu, 1, K);
    } else {
        int kc = (K / ksplit + 15) & ~15;
        dim3 grid(M / 64, Nn / 64, ksplit);
        gemm64<<<grid, 256, 0, st>>>(A, W, W2, sgn, nullptr, nullptr, part,
                                     M, Nn, K, lda, ldw, ldc, 0, 0, 0, 0,
                                     0, ksplit, kc);
        ksum_kernel<<<(M * Nn / 4 + 255) / 256, 256, 0, st>>>(part, bias, C, M, Nn, ldc,
                                                              ksplit, relu);
    }
}

extern "C" void kernel_launch(void* const* d_in, const int* in_sizes, int n_in,
                              void* d_out, int out_size, void* d_ws, size_t ws_size,
                              hipStream_t stream)
{
    const float* sup    = (const float*)d_in[0];
    const float* qry    = (const float*)d_in[1];
    const float* sim_w1 = (const float*)d_in[3];
    const float* sim_b1 = (const float*)d_in[4];
    const float* sim_w2 = (const float*)d_in[5];
    const float* sim_b2 = (const float*)d_in[6];
    const float* div_w1 = (const float*)d_in[7];
    const float* div_b1 = (const float*)d_in[8];
    const float* div_w2 = (const float*)d_in[9];
    const float* div_b2 = (const float*)d_in[10];
    const float* dis_w1 = (const float*)d_in[11];
    const float* dis_b1 = (const float*)d_in[12];
    const float* dis_w2 = (const float*)d_in[13];
    const float* dis_b2 = (const float*)d_in[14];
    const float* dis_g  = (const float*)d_in[15];
    const float* dis_bb = (const float*)d_in[16];
    const float* rel_W  = (const float*)d_in[17];
    const float* rel_b  = (const float*)d_in[18];
    const float* agg_w1 = (const float*)d_in[19];
    const float* agg_b1 = (const float*)d_in[20];
    const float* agg_w2 = (const float*)d_in[21];
    const float* agg_b2 = (const float*)d_in[22];
    const float* wq = (const float*)d_in[23];
    const float* bq = (const float*)d_in[24];
    const float* wk = (const float*)d_in[25];
    const float* bk = (const float*)d_in[26];
    const float* wv = (const float*)d_in[27];
    const float* bv = (const float*)d_in[28];
    const float* wo = (const float*)d_in[29];
    const float* bo = (const float*)d_in[30];
    const float* ln_g = (const float*)d_in[31];
    const float* ln_b = (const float*)d_in[32];
    const float* cls_w1 = (const float*)d_in[33];
    const float* cls_b1 = (const float*)d_in[34];
    const float* cls_w2 = (const float*)d_in[35];
    const float* cls_b2 = (const float*)d_in[36];

    const int NH = NT * H;          // 196608
    const int HH = H * H;           // 589824

    // workspace layout (fp32)
    float* ws = (float*)d_ws;
    float* f       = ws;
    float* fa_s    = f      + NH;
    float* fb_s    = fa_s   + NH;
    float* fa_d    = fb_s   + NH;
    float* fb_d    = fa_d   + NH;
    float* comb    = fb_d   + NH;          // 16*256*256, layout [r][i][j]
    float* xA      = comb   + 1048576;
    float* xB      = xA     + NH;
    float* hid384  = xB     + NH;          // 256*384
    float* t_buf   = hid384 + 98304;       // 16*256*768 = 3145728 — doubles as split-K partial buf
    float* agg     = t_buf  + 3145728;     // 256*12288
    float* hidA    = agg    + 3145728;
    float* a_buf   = hidA   + NH;
    float* q_buf   = a_buf  + NH;
    float* k_buf   = q_buf  + NH;
    float* kT_buf  = k_buf  + NH;
    float* v_buf   = kT_buf + NH;
    float* o_buf   = v_buf  + NH;
    float* tmp_o   = o_buf  + NH;
    float* cls_hid = tmp_o  + NH;          // 192*384
    size_t need = (size_t)((cls_hid + 73728) - ws) * sizeof(float);
    if (ws_size < need) return;

    float* part = t_buf;   // split-K partials alias t_buf (max 16*256*768 = its full size);
                           // t_buf is only live from rel-einsum write to agg read, during
                           // which all GEMMs use ksplit==1.

    // output layout (fp32): preds(576), x(196608), sim(1048576), div(1048576)
    float* out       = (float*)d_out;
    float* out_preds = out;
    float* out_x     = out + 576;
    float* out_sim   = out_x + NH;
    float* out_div   = out_sim + 1048576;

    // 1. f = concat
    build_f_kernel<<<(NH + 255) / 256, 256, 0, stream>>>(sup, qry, f);

    // 2. fa/fb for sim and div   (div: wa' = da+db, wb' = db-da)
    gemm(stream, f, sim_w1,      nullptr,      0.f, nullptr, fa_s, part, NT, H, H, H, H, H, 0,0,0,0, 0, 1, 8);
    gemm(stream, f, sim_w1 + HH, nullptr,      0.f, nullptr, fb_s, part, NT, H, H, H, H, H, 0,0,0,0, 0, 1, 8);
    gemm(stream, f, div_w1,      div_w1 + HH,  1.f, nullptr, fa_d, part, NT, H, H, H, H, H, 0,0,0,0, 0, 1, 8);
    gemm(stream, f, div_w1 + HH, div_w1,      -1.f, nullptr, fb_d, part, NT, H, H, H, H, H, 0,0,0,0, 0, 1, 8);

    // 3. relations (sim writes comb, div accumulates)
    relations_kernel<<<dim3(32, 8), 256, 0, stream>>>(fa_s, fb_s, sim_b1, sim_w2, sim_b2,
                                                      out_sim, comb, 0.6f, 0);
    relations_kernel<<<dim3(32, 8), 256, 0, stream>>>(fa_d, fb_d, div_b1, div_w2, div_b2,
                                                      out_div, comb, 0.4f, 1);

    // 4. distill MLP + LN -> x
    gemm(stream, f, dis_w1, nullptr, 0.f, dis_b1, hid384, part, NT, 384, H, H, 384, 384, 0,0,0,0, 1, 1, 16);
    gemm(stream, hid384, dis_w2, nullptr, 0.f, dis_b2, tmp_o, part, NT, H, 384, 384, H, H, 0,0,0,0, 0, 1, 8);
    ln_kernel<<<NT, 256, 0, stream>>>(tmp_o, nullptr, dis_g, dis_bb, xA);

    float* x_cur = xA;
    float* x_nxt = xB;
    for (int l = 0; l < NL; ++l) {
        const float* relW_l = rel_W + (long long)l * R * HH;
        const float* relb_l = rel_b + l * R * H;
        // t[r] = x @ rel_W[l,r] + rel_b[l,r]   (16 batches)
        gemm(stream, x_cur, relW_l, nullptr, 0.f, relb_l, t_buf, nullptr,
             NT, H, H, H, H, H, 0, (long long)HH, (long long)NH, H, 0, R, 1);
        // agg[i, r*H+h] = sum_j comb[r,i,j] * t[r,j,h]   (16 batches)
        gemm(stream, comb, t_buf, nullptr, 0.f, nullptr, agg, nullptr,
             NT, H, NT, NT, H, R * H, (long long)NT * NT, (long long)NH, H, 0, 0, R, 1);
        // agg MLP
        gemm(stream, agg, agg_w1 + (long long)l * R * H * H, nullptr, 0.f,
             agg_b1 + l * H, hidA, part, NT, H, R * H, R * H, H, H, 0,0,0,0, 1, 1, 16);
        gemm(stream, hidA, agg_w2 + (long long)l * HH, nullptr, 0.f,
             agg_b2 + l * H, a_buf, part, NT, H, H, H, H, H, 0,0,0,0, 0, 1, 8);
        // q from a, k/v from x
        gemm(stream, a_buf, wq + (long long)l * HH, nullptr, 0.f, bq + l * H, q_buf, part,
             NT, H, H, H, H, H, 0,0,0,0, 0, 1, 8);
        gemm(stream, x_cur, wk + (long long)l * HH, nullptr, 0.f, bk + l * H, k_buf, part,
             NT, H, H, H, H, H, 0,0,0,0, 0, 1, 8);
        gemm(stream, x_cur, wv + (long long)l * HH, nullptr, 0.f, bv + l * H, v_buf, part,
             NT, H, H, H, H, H, 0,0,0,0, 0, 1, 8);
        transpose_kernel<<<dim3(H / 32, NT / 32), dim3(32, 32), 0, stream>>>(k_buf, kT_buf, NT, H);
        attn_kernel<<<dim3(NHEADS, NT), 256, 0, stream>>>(q_buf, kT_buf, v_buf, o_buf);
        gemm(stream, o_buf, wo + (long long)l * HH, nullptr, 0.f, bo + l * H, tmp_o, part,
             NT, H, H, H, H, H, 0,0,0,0, 0, 1, 8);
        float* dst = (l == NL - 1) ? out_x : x_nxt;
        ln_kernel<<<NT, 256, 0, stream>>>(tmp_o, x_cur, ln_g + l * H, ln_b + l * H, dst);
        x_nxt = x_cur; x_cur = dst;
    }

    // classifier on query rows
    gemm(stream, x_cur + (long long)NS * H, cls_w1, nullptr, 0.f, cls_b1, cls_hid, part,
         192, 384, H, H, 384, 384, 0,0,0,0, 1, 1, 16);
    cls_final_kernel<<<192, 64, 0, stream>>>(cls_hid, cls_w2, cls_b2, out_preds);
}